// Round 2
// baseline (2201.917 us; speedup 1.0000x reference)
//
#include <hip/hip_runtime.h>
#include <math.h>

// Problem constants (from reference)
#define N_SAMP 441000
#define BATCH  16
#define CHUNK  8192
#define WARM   32768
#define NCHUNK 54                      // ceil(441000/8192)
#define NTHREAD (BATCH * NCHUNK)       // 864

// exp(-1/441), exp(-1/4410) to double precision; compiler rounds to f32
#define A_AT  0.9977349953069123f
#define A_REL 0.9997732683378945f
#define OMA_AT  (1.0f - A_AT)
#define OMA_REL (1.0f - A_REL)

// 20*log10(z) = 6.020599913279624 * log2(z)
static __device__ __forceinline__ float rect_db_f(float xv) {
    return 6.020599913279624f * log2f(fabsf(xv) + 1e-8f);
}

// s' = max(A_AT*s + p, A_REL*s + q)  with p=(1-A_AT)*v, q=(1-A_REL)*v
static __device__ __forceinline__ float step_s(float s, float p, float q) {
    return fmaxf(fmaf(A_AT, s, p), fmaf(A_REL, s, q));
}

static __device__ __forceinline__ float step_v(float s, float v) {
    return step_s(s, OMA_AT * v, OMA_REL * v);
}

// gain multiplier from smoothed level s, threshold_db th, depth dp
static __device__ __forceinline__ float gain_mul(float s, float th, float dp) {
    float ddn = s - th;
    float gdn = 0.0f;
    if (ddn > -0.1f) {
        float dm = ddn - 0.1f;
        gdn = -0.4925037481259370f * (ddn + 0.1f + sqrtf(fmaf(dm, dm, 1e-4f)));
    }
    float dup = th - s;
    float gup = 0.0f;
    if (dup > -0.1f) {
        float um = dup - 0.1f;
        gup = 0.45f * (dup + 0.1f + sqrtf(fmaf(um, um, 1e-4f)));
    }
    gup = fminf(gup, 36.0f);
    float gdb = (gdn + gup) * dp;
    // 10^(gdb/20) = 2^(gdb * log2(10)/20)
    return exp2f(gdb * 0.1660964047443681f);
}

// Pass 0: per-sample p,q precompute (fully parallel, memory-bound)
__global__ __launch_bounds__(256) void pq_kernel(const float* __restrict__ x,
                                                 float4* __restrict__ pq4) {
    int i = blockIdx.x * blockDim.x + threadIdx.x;   // group of 4 samples
    const int ngrp = (BATCH * N_SAMP) / 4;
    if (i >= ngrp) return;
    float4 xv = ((const float4*)x)[i];
    float v0 = rect_db_f(xv.x), v1 = rect_db_f(xv.y);
    float v2 = rect_db_f(xv.z), v3 = rect_db_f(xv.w);
    pq4[2 * i]     = make_float4(OMA_AT * v0, OMA_REL * v0, OMA_AT * v1, OMA_REL * v1);
    pq4[2 * i + 1] = make_float4(OMA_AT * v2, OMA_REL * v2, OMA_AT * v3, OMA_REL * v3);
}

// Pass 1: serial scan per chunk with warmup; minimal per-sample work
__global__ __launch_bounds__(64) void scan_kernel(const float2* __restrict__ pq,
                                                  float* __restrict__ level) {
    int t = blockIdx.x * 64 + threadIdx.x;
    if (t >= NTHREAD) return;
    int b = t / NCHUNK;
    int k = t - b * NCHUNK;
    int start = k * CHUNK;
    int end = min(start + CHUNK, N_SAMP);
    int w0 = max(start - WARM, 0);

    const float2* row = pq + (size_t)b * N_SAMP;
    // seed: v at w0 recovered from p = (1-A_AT)*v
    float s = row[w0].x * (1.0f / OMA_AT);

    #pragma unroll 2
    for (int j = w0; j < start; j += 4) {
        float4 ab = *(const float4*)(row + j);       // p0 q0 p1 q1
        float4 cd = *(const float4*)(row + j + 2);   // p2 q2 p3 q3
        s = step_s(s, ab.x, ab.y);
        s = step_s(s, ab.z, ab.w);
        s = step_s(s, cd.x, cd.y);
        s = step_s(s, cd.z, cd.w);
    }

    float* lrow = level + (size_t)b * N_SAMP;
    #pragma unroll 2
    for (int j = start; j < end; j += 4) {
        float4 ab = *(const float4*)(row + j);
        float4 cd = *(const float4*)(row + j + 2);
        float l0 = step_s(s,  ab.x, ab.y);
        float l1 = step_s(l0, ab.z, ab.w);
        float l2 = step_s(l1, cd.x, cd.y);
        float l3 = step_s(l2, cd.z, cd.w);
        s = l3;
        *(float4*)(lrow + j) = make_float4(l0, l1, l2, l3);
    }
}

// Pass 2: gain + output (fully parallel, memory-bound)
__global__ __launch_bounds__(256) void out_kernel(const float* __restrict__ x,
                                                  const float* __restrict__ level,
                                                  const float* __restrict__ thr,
                                                  const float* __restrict__ dep,
                                                  float* __restrict__ out) {
    int i = blockIdx.x * blockDim.x + threadIdx.x;   // group of 4 samples
    const int ngrp = (BATCH * N_SAMP) / 4;
    if (i >= ngrp) return;
    int b = (i * 4) / N_SAMP;                        // groups never straddle rows (N%4==0)
    float th = fmaf(thr[b], 40.0f, -40.0f);          // TMIN + thr*(TMAX-TMIN)
    float dp = dep[b];
    float4 xv = ((const float4*)x)[i];
    float4 lv = ((const float4*)level)[i];
    float4 o;
    o.x = xv.x * gain_mul(lv.x, th, dp);
    o.y = xv.y * gain_mul(lv.y, th, dp);
    o.z = xv.z * gain_mul(lv.z, th, dp);
    o.w = xv.w * gain_mul(lv.w, th, dp);
    ((float4*)out)[i] = o;
}

// Fallback: fully fused, zero-workspace variant (slower, used only if ws too small)
__global__ __launch_bounds__(64) void scan_fused(const float* __restrict__ x,
                                                 const float* __restrict__ thr,
                                                 const float* __restrict__ dep,
                                                 float* __restrict__ out) {
    int t = blockIdx.x * 64 + threadIdx.x;
    if (t >= NTHREAD) return;
    int b = t / NCHUNK;
    int k = t - b * NCHUNK;
    int start = k * CHUNK;
    int end = min(start + CHUNK, N_SAMP);
    int w0 = max(start - WARM, 0);

    const float* xr = x + (size_t)b * N_SAMP;
    float th = fmaf(thr[b], 40.0f, -40.0f);
    float dp = dep[b];
    float s = rect_db_f(xr[w0]);

    for (int j = w0; j < start; j += 4) {
        float4 xv = *(const float4*)(xr + j);
        s = step_v(s, rect_db_f(xv.x));
        s = step_v(s, rect_db_f(xv.y));
        s = step_v(s, rect_db_f(xv.z));
        s = step_v(s, rect_db_f(xv.w));
    }
    float* orow = out + (size_t)b * N_SAMP;
    for (int j = start; j < end; j += 4) {
        float4 xv = *(const float4*)(xr + j);
        float l0 = step_v(s,  rect_db_f(xv.x));
        float l1 = step_v(l0, rect_db_f(xv.y));
        float l2 = step_v(l1, rect_db_f(xv.z));
        float l3 = step_v(l2, rect_db_f(xv.w));
        s = l3;
        float4 o;
        o.x = xv.x * gain_mul(l0, th, dp);
        o.y = xv.y * gain_mul(l1, th, dp);
        o.z = xv.z * gain_mul(l2, th, dp);
        o.w = xv.w * gain_mul(l3, th, dp);
        *(float4*)(orow + j) = o;
    }
}

extern "C" void kernel_launch(void* const* d_in, const int* in_sizes, int n_in,
                              void* d_out, int out_size, void* d_ws, size_t ws_size,
                              hipStream_t stream) {
    const float* x   = (const float*)d_in[0];
    const float* thr = (const float*)d_in[1];
    const float* dep = (const float*)d_in[2];
    float* out = (float*)d_out;

    const size_t pq_bytes = (size_t)BATCH * N_SAMP * 2 * sizeof(float);   // 56.4 MB
    const size_t lv_bytes = (size_t)BATCH * N_SAMP * sizeof(float);       // 28.2 MB
    const int ngrp = (BATCH * N_SAMP) / 4;

    if (ws_size >= pq_bytes + lv_bytes) {
        float2* pq    = (float2*)d_ws;
        float*  level = (float*)((char*)d_ws + pq_bytes);
        pq_kernel<<<(ngrp + 255) / 256, 256, 0, stream>>>(x, (float4*)pq);
        scan_kernel<<<(NTHREAD + 63) / 64, 64, 0, stream>>>(pq, level);
        out_kernel<<<(ngrp + 255) / 256, 256, 0, stream>>>(x, level, thr, dep, out);
    } else {
        scan_fused<<<(NTHREAD + 63) / 64, 64, 0, stream>>>(x, thr, dep, out);
    }
}

// Round 3
// 558.689 us; speedup vs baseline: 3.9412x; 3.9412x over previous
//
#include <hip/hip_runtime.h>
#include <math.h>

// ---- problem constants ----
#define N_SAMP 441000
#define BATCH  16
#define N_Q    110250          // N_SAMP/4 quads per row
#define KQ_PAD 110592          // padded quads (multiple of 8; covers scan overrun)
#define CHUNK_Q 1024           // chunk length in quads (4096 samples)
#define WARM_Q  8192           // warmup length in quads (32768 samples)
#define NCHUNK 108             // 108*1024 quads = 110592 >= 110250
#define NWAVE  27              // 108 chunks / 4 per wave
#define PSTR4  442368          // plane stride in float4 units (KQ_PAD/4 * 16)

#define A_AT  0.9977349953069123f
#define A_REL 0.9997732683378945f
#define OMA_AT  (1.0f - A_AT)
#define OMA_REL (1.0f - A_REL)

static __device__ __forceinline__ float rect_db_f(float xv) {
    return 6.020599913279624f * log2f(fabsf(xv) + 1e-8f);
}
static __device__ __forceinline__ float step_v(float s, float v) {
    return fmaxf(fmaf(A_AT, s, OMA_AT * v), fmaf(A_REL, s, OMA_REL * v));
}
static __device__ __forceinline__ float gain_mul(float s, float th, float dp) {
    float ddn = s - th;
    float gdn = 0.0f;
    if (ddn > -0.1f) {
        float dm = ddn - 0.1f;
        gdn = -0.4925037481259370f * (ddn + 0.1f + sqrtf(fmaf(dm, dm, 1e-4f)));
    }
    float dup = th - s;
    float gup = 0.0f;
    if (dup > -0.1f) {
        float um = dup - 0.1f;
        gup = 0.45f * (dup + 0.1f + sqrtf(fmaf(um, um, 1e-4f)));
    }
    gup = fminf(gup, 36.0f);
    return exp2f((gdn + gup) * dp * 0.1660964047443681f);
}

// ---- Pass 0: per-quad composite coefficients (parallel DP) ----
// 4-step composition of s'=max(a*s+p, r*s+q) is max over 5 slope classes
// c = #attack-steps: s'' = max_c( a^c r^(4-c) * s + K_c ).  K_c via DP.
// Layout: K[c][gq][b][slot] i.e. float idx c*4*PSTR4 + (t>>2)*64 + b*4 + (t&3)
__global__ __launch_bounds__(256) void coef_kernel(const float* __restrict__ x,
                                                   float* __restrict__ K) {
    int t = blockIdx.x * 256 + threadIdx.x;   // quad index
    int b = blockIdx.y;
    if (t >= N_Q) return;
    float4 xq = ((const float4*)x)[b * N_Q + t];
    float v0 = rect_db_f(xq.x), v1 = rect_db_f(xq.y);
    float v2 = rect_db_f(xq.z), v3 = rect_db_f(xq.w);
    float p0 = OMA_AT * v0, q0 = OMA_REL * v0;
    float p1 = OMA_AT * v1, q1 = OMA_REL * v1;
    float p2 = OMA_AT * v2, q2 = OMA_REL * v2;
    float p3 = OMA_AT * v3, q3 = OMA_REL * v3;
    // DP over classes (index = #attacks so far)
    float o1_1 = p0, o1_0 = q0;
    float o2_2 = fmaf(A_AT, o1_1, p1);
    float o2_1 = fmaxf(fmaf(A_AT, o1_0, p1), fmaf(A_REL, o1_1, q1));
    float o2_0 = fmaf(A_REL, o1_0, q1);
    float o3_3 = fmaf(A_AT, o2_2, p2);
    float o3_2 = fmaxf(fmaf(A_AT, o2_1, p2), fmaf(A_REL, o2_2, q2));
    float o3_1 = fmaxf(fmaf(A_AT, o2_0, p2), fmaf(A_REL, o2_1, q2));
    float o3_0 = fmaf(A_REL, o2_0, q2);
    float K4 = fmaf(A_AT, o3_3, p3);
    float K3 = fmaxf(fmaf(A_AT, o3_2, p3), fmaf(A_REL, o3_3, q3));
    float K2 = fmaxf(fmaf(A_AT, o3_1, p3), fmaf(A_REL, o3_2, q3));
    float K1 = fmaxf(fmaf(A_AT, o3_0, p3), fmaf(A_REL, o3_1, q3));
    float K0 = fmaf(A_REL, o3_0, q3);
    int base = (t >> 2) * 64 + b * 4 + (t & 3);
    K[base]                 = K0;
    K[base + 4 * PSTR4]     = K1;
    K[base + 8 * PSTR4]     = K2;
    K[base + 12 * PSTR4]    = K3;
    K[base + 16 * PSTR4]    = K4;
}

// ---- Pass 1: serial scan over quads; wave = 4 chunks x 16 batches ----
__global__ __launch_bounds__(64) void scan_kernel(const float* __restrict__ Kf,
                                                  const float* __restrict__ x,
                                                  float* __restrict__ level_q) {
    const int w    = blockIdx.x;            // 0..26
    const int lane = threadIdx.x;
    const int grp  = lane >> 4;             // 0..3
    const int b    = lane & 15;
    const int k    = 4 * w + grp;           // chunk id 0..107
    const int g0   = max(0, (k - 8) * CHUNK_Q);       // warmup start (quads)
    const int L    = min(WARM_Q + CHUNK_Q, (4 * w + 4) * CHUNK_Q); // iters (wave-uniform)
    const int nblk = L / 8;
    const int emit_blk0 = (w >= 2) ? (WARM_Q / 8) : 0; // w<2: g0==0, all exact -> store all

    // slope constants (f32 constant-folded)
    const float S0 = A_REL * A_REL * A_REL * A_REL;
    const float S1 = A_AT * A_REL * A_REL * A_REL;
    const float S2 = A_AT * A_AT * A_REL * A_REL;
    const float S3 = A_AT * A_AT * A_AT * A_REL;
    const float S4 = A_AT * A_AT * A_AT * A_AT;

    const float4* K4p = (const float4*)Kf;
    const float4* pc0 = K4p + 0 * (size_t)PSTR4 + (size_t)(g0 >> 2) * 16 + b;
    const float4* pc1 = K4p + 1 * (size_t)PSTR4 + (size_t)(g0 >> 2) * 16 + b;
    const float4* pc2 = K4p + 2 * (size_t)PSTR4 + (size_t)(g0 >> 2) * 16 + b;
    const float4* pc3 = K4p + 3 * (size_t)PSTR4 + (size_t)(g0 >> 2) * 16 + b;
    const float4* pc4 = K4p + 4 * (size_t)PSTR4 + (size_t)(g0 >> 2) * 16 + b;
    float* lp = level_q + (size_t)b * KQ_PAD + g0;

    // seed: level before window := v at first window sample (exact when g0==0)
    float s = rect_db_f(x[(size_t)b * N_SAMP + 4 * g0]);

    // ring prefetch: 4 rings x (5 planes x 2 float4 = 8 quads)
    float4 buf[4][5][2];
    #pragma unroll
    for (int r = 0; r < 3; ++r) {
        #pragma unroll
        for (int h = 0; h < 2; ++h) {
            int gi = (r * 2 + h) * 16;
            buf[r][0][h] = pc0[gi]; buf[r][1][h] = pc1[gi]; buf[r][2][h] = pc2[gi];
            buf[r][3][h] = pc3[gi]; buf[r][4][h] = pc4[gi];
        }
    }

    const int nblk4 = nblk / 4;   // nblk in {512,1024,1152}, all %4==0
    for (int blk4 = 0; blk4 < nblk4; ++blk4) {
        #pragma unroll
        for (int j = 0; j < 4; ++j) {
            const int blk = blk4 * 4 + j;
            // prefetch blk+3 into ring (j+3)&3
            if (blk + 3 < nblk) {
                const int rp = (j + 3) & 3;
                #pragma unroll
                for (int h = 0; h < 2; ++h) {
                    int gi = ((blk + 3) * 2 + h) * 16;
                    buf[rp][0][h] = pc0[gi]; buf[rp][1][h] = pc1[gi];
                    buf[rp][2][h] = pc2[gi]; buf[rp][3][h] = pc3[gi];
                    buf[rp][4][h] = pc4[gi];
                }
            }
            // compute ring j (8 quads)
            const bool do_store = (blk >= emit_blk0);
            #pragma unroll
            for (int q = 0; q < 8; ++q) {
                const int h = q >> 2, e = q & 3;
                float k0 = ((const float*)&buf[j][0][h])[e];
                float k1 = ((const float*)&buf[j][1][h])[e];
                float k2 = ((const float*)&buf[j][2][h])[e];
                float k3 = ((const float*)&buf[j][3][h])[e];
                float k4 = ((const float*)&buf[j][4][h])[e];
                float c0 = fmaf(S0, s, k0);
                float c1 = fmaf(S1, s, k1);
                float c2 = fmaf(S2, s, k2);
                float c3 = fmaf(S3, s, k3);
                float c4 = fmaf(S4, s, k4);
                s = fmaxf(fmaxf(fmaxf(c0, c1), fmaxf(c2, c3)), c4);
                if (do_store) lp[blk * 8 + q] = s;
            }
        }
    }
}

// ---- Pass 2: intra-quad reconstruction + gain + output (parallel) ----
__global__ __launch_bounds__(256) void out_kernel(const float* __restrict__ x,
                                                  const float* __restrict__ level_q,
                                                  const float* __restrict__ thr,
                                                  const float* __restrict__ dep,
                                                  float* __restrict__ out) {
    int t = blockIdx.x * 256 + threadIdx.x;   // quad index
    int b = blockIdx.y;
    if (t >= N_Q) return;
    float4 xq = ((const float4*)x)[b * N_Q + t];
    float v0 = rect_db_f(xq.x), v1 = rect_db_f(xq.y);
    float v2 = rect_db_f(xq.z), v3 = rect_db_f(xq.w);
    float s = (t == 0) ? v0 : level_q[(size_t)b * KQ_PAD + t - 1];
    float l0 = step_v(s, v0);
    float l1 = step_v(l0, v1);
    float l2 = step_v(l1, v2);
    float l3 = step_v(l2, v3);
    float th = fmaf(thr[b], 40.0f, -40.0f);
    float dp = dep[b];
    float4 o;
    o.x = xq.x * gain_mul(l0, th, dp);
    o.y = xq.y * gain_mul(l1, th, dp);
    o.z = xq.z * gain_mul(l2, th, dp);
    o.w = xq.w * gain_mul(l3, th, dp);
    ((float4*)out)[b * N_Q + t] = o;
}

// ---- Fallback (tiny ws): slow but correct fused scan ----
__global__ __launch_bounds__(64) void scan_fused(const float* __restrict__ x,
                                                 const float* __restrict__ thr,
                                                 const float* __restrict__ dep,
                                                 float* __restrict__ out) {
    int t = blockIdx.x * 64 + threadIdx.x;
    const int NCH = 54, CH = 8192, WM = 32768;
    if (t >= BATCH * NCH) return;
    int b = t / NCH, k = t - b * NCH;
    int start = k * CH, end = min(start + CH, N_SAMP), w0 = max(start - WM, 0);
    const float* xr = x + (size_t)b * N_SAMP;
    float th = fmaf(thr[b], 40.0f, -40.0f);
    float dp = dep[b];
    float s = rect_db_f(xr[w0]);
    for (int j = w0; j < start; ++j) s = step_v(s, rect_db_f(xr[j]));
    float* orow = out + (size_t)b * N_SAMP;
    for (int j = start; j < end; ++j) {
        float xv = xr[j];
        s = step_v(s, rect_db_f(xv));
        orow[j] = xv * gain_mul(s, th, dp);
    }
}

extern "C" void kernel_launch(void* const* d_in, const int* in_sizes, int n_in,
                              void* d_out, int out_size, void* d_ws, size_t ws_size,
                              hipStream_t stream) {
    const float* x   = (const float*)d_in[0];
    const float* thr = (const float*)d_in[1];
    const float* dep = (const float*)d_in[2];
    float* out = (float*)d_out;

    const size_t k_bytes  = (size_t)5 * PSTR4 * 16;          // 35.4 MB
    const size_t lq_bytes = (size_t)BATCH * KQ_PAD * 4;      // 7.08 MB

    if (ws_size >= k_bytes + lq_bytes) {
        float* K       = (float*)d_ws;
        float* level_q = (float*)((char*)d_ws + k_bytes);
        dim3 gpar((N_Q + 255) / 256, BATCH);
        coef_kernel<<<gpar, 256, 0, stream>>>(x, K);
        scan_kernel<<<NWAVE, 64, 0, stream>>>(K, x, level_q);
        out_kernel<<<gpar, 256, 0, stream>>>(x, level_q, thr, dep, out);
    } else {
        scan_fused<<<(BATCH * 54 + 63) / 64, 64, 0, stream>>>(x, thr, dep, out);
    }
}